// Round 2
// baseline (373.552 us; speedup 1.0000x reference)
//
#include <hip/hip_runtime.h>

#define K_DIM 2048
#define N_DIM 2048
#define M_DIM 16384

typedef int v4i __attribute__((ext_vector_type(4)));
typedef int v16i __attribute__((ext_vector_type(16)));

// ---------------- ws layout ----------------
// [0]       double part[256]      (2 KB)
// [2048]    float  invsw          (= clip(mean|W|,1e-5))
// [4096]    float  si[16384]      (64 KB)
// [69632]   int8   qw[2048*2048]  (4 MiB)
// [4263936] int8   qx[16384*2048] (32 MiB)

__device__ __forceinline__ void lds16(const void* g, void* l) {
    __builtin_amdgcn_global_load_lds(
        (const __attribute__((address_space(1))) unsigned int*)g,
        (__attribute__((address_space(3))) unsigned int*)l,
        16, 0, 0);
}

// ---------- kernel 1: per-block |W| partial sums (no atomics) ----------
__global__ __launch_bounds__(256) void k_wsum(const float* __restrict__ w,
                                              double* __restrict__ part) {
    int tid = blockIdx.x * 256 + threadIdx.x;
    int stride = gridDim.x * 256;
    const float4* w4 = (const float4*)w;
    double s = 0.0;
    for (int i = tid; i < (N_DIM * K_DIM / 4); i += stride) {
        float4 v = w4[i];
        s += (double)fabsf(v.x);
        s += (double)fabsf(v.y);
        s += (double)fabsf(v.z);
        s += (double)fabsf(v.w);
    }
#pragma unroll
    for (int off = 32; off; off >>= 1) s += __shfl_xor(s, off, 64);
    __shared__ double sp[4];
    int lane = threadIdx.x & 63, wv = threadIdx.x >> 6;
    if (lane == 0) sp[wv] = s;
    __syncthreads();
    if (threadIdx.x == 0) part[blockIdx.x] = sp[0] + sp[1] + sp[2] + sp[3];
}

// ---------- kernel 2: reduce partials -> invsw (single block) ----------
__global__ __launch_bounds__(256) void k_wred(const double* __restrict__ part,
                                              float* __restrict__ invsw_out) {
    double s = part[threadIdx.x];
#pragma unroll
    for (int off = 32; off; off >>= 1) s += __shfl_xor(s, off, 64);
    __shared__ double sp[4];
    int lane = threadIdx.x & 63, wv = threadIdx.x >> 6;
    if (lane == 0) sp[wv] = s;
    __syncthreads();
    if (threadIdx.x == 0) {
        double total = sp[0] + sp[1] + sp[2] + sp[3];
        float mean = (float)(total * (1.0 / (double)(N_DIM * K_DIM)));
        *invsw_out = fmaxf(mean, 1e-5f);
    }
}

// ---------- kernel 3: ternary-quantize W ----------
__global__ __launch_bounds__(256) void k_quant_w(const float* __restrict__ w,
                                                 signed char* __restrict__ qw,
                                                 const float* __restrict__ invsw_p) {
    float sw = 1.0f / (*invsw_p);  // reference's sw
    int tid = blockIdx.x * 256 + threadIdx.x;
    float4 v = ((const float4*)w)[tid];
    int q0 = (int)fminf(fmaxf(rintf(v.x * sw), -1.f), 1.f);
    int q1 = (int)fminf(fmaxf(rintf(v.y * sw), -1.f), 1.f);
    int q2 = (int)fminf(fmaxf(rintf(v.z * sw), -1.f), 1.f);
    int q3 = (int)fminf(fmaxf(rintf(v.w * sw), -1.f), 1.f);
    ((int*)qw)[tid] = (q0 & 255) | ((q1 & 255) << 8) | ((q2 & 255) << 16) | ((q3 & 255) << 24);
}

// ---------- kernel 4: per-row int8-quantize X (1 wave per row) ----------
__global__ __launch_bounds__(256) void k_quant_x(const float* __restrict__ x,
                                                 signed char* __restrict__ qx,
                                                 float* __restrict__ si_out) {
    int row = blockIdx.x * 4 + (threadIdx.x >> 6);
    int lane = threadIdx.x & 63;
    const float4* xr = (const float4*)(x + (size_t)row * K_DIM);
    float4 v[8];
    float mx = 0.f;
#pragma unroll
    for (int c = 0; c < 8; c++) {
        v[c] = xr[c * 64 + lane];
        mx = fmaxf(mx, fmaxf(fmaxf(fabsf(v[c].x), fabsf(v[c].y)),
                             fmaxf(fabsf(v[c].z), fabsf(v[c].w))));
    }
#pragma unroll
    for (int off = 32; off; off >>= 1) mx = fmaxf(mx, __shfl_xor(mx, off, 64));
    float si = 127.0f / fmaxf(mx, 1e-5f);  // bit-exact vs reference
    if (lane == 0) si_out[row] = si;
    int* qr = (int*)(qx + (size_t)row * K_DIM);
#pragma unroll
    for (int c = 0; c < 8; c++) {
        int q0 = (int)fminf(fmaxf(rintf(v[c].x * si), -128.f), 127.f);
        int q1 = (int)fminf(fmaxf(rintf(v[c].y * si), -128.f), 127.f);
        int q2 = (int)fminf(fmaxf(rintf(v[c].z * si), -128.f), 127.f);
        int q3 = (int)fminf(fmaxf(rintf(v[c].w * si), -128.f), 127.f);
        qr[c * 64 + lane] = (q0 & 255) | ((q1 & 255) << 8) | ((q2 & 255) << 16) | ((q3 & 255) << 24);
    }
}

// ---------- kernel 5: int8 GEMM, 256x128 block, 32x32x32 MFMA, k-major LDS ----------
// C[m][n] = sum_k qx[m][k]*qw[n][k]; out = fp16_round(C * (invsw/si))
// LDS layout: As[k16][row] (k16=0..3, row=0..255, 16B granules) -> ds_read_b128
// is 512B-contiguous per 32-lane half => conflict-free. Staging slot j*256+t
// satisfies global_load_lds's lane-contiguous LDS constraint.
__global__ __launch_bounds__(256, 2) void k_gemm(const signed char* __restrict__ qx,
                                                 const signed char* __restrict__ qw,
                                                 const float* __restrict__ si,
                                                 const float* __restrict__ invsw_p,
                                                 float* __restrict__ out) {
    __shared__ __align__(16) signed char As[16384];  // 4 x 256 x 16B
    __shared__ __align__(16) signed char Bs[8192];   // 4 x 128 x 16B
    const int t = threadIdx.x;
    const int lane = t & 63, wv = t >> 6;
    const int wr = wv >> 1, wc = wv & 1;   // 2x2 wave grid; wave tile 128x64
    const int l31 = lane & 31, lh = lane >> 5;
    const int bn = blockIdx.x, bm = blockIdx.y;

    // staging sources: A row = bm*256+t (one 64B line per kstep per thread)
    const signed char* aG = qx + (size_t)(bm * 256 + t) * K_DIM;
    // B slot j*256+t -> k16 = 2j + (t>>7), nrow = t&127
    const signed char* bG = qw + (size_t)(bn * 128 + (t & 127)) * K_DIM + ((t >> 7) << 4);
    const int t16 = t << 4;

    v16i acc[4][2] = {};

    for (int k0 = 0; k0 < K_DIM; k0 += 64) {
        lds16(aG + k0,      As + t16);
        lds16(aG + k0 + 16, As + 4096 + t16);
        lds16(aG + k0 + 32, As + 8192 + t16);
        lds16(aG + k0 + 48, As + 12288 + t16);
        lds16(bG + k0,      Bs + t16);
        lds16(bG + k0 + 32, Bs + 4096 + t16);
        __syncthreads();

#pragma unroll
        for (int ks = 0; ks < 2; ks++) {
            v4i af[4], bf[2];
#pragma unroll
            for (int mt = 0; mt < 4; mt++)
                af[mt] = *(const v4i*)(As + (((ks * 2 + lh) * 256 + wr * 128 + mt * 32 + l31) << 4));
#pragma unroll
            for (int nt = 0; nt < 2; nt++)
                bf[nt] = *(const v4i*)(Bs + (((ks * 2 + lh) * 128 + wc * 64 + nt * 32 + l31) << 4));
#pragma unroll
            for (int mt = 0; mt < 4; mt++)
#pragma unroll
                for (int nt = 0; nt < 2; nt++)
                    acc[mt][nt] = __builtin_amdgcn_mfma_i32_32x32x32_i8(af[mt], bf[nt], acc[mt][nt], 0, 0, 0);
        }
        __syncthreads();
    }

    // epilogue: C/D 32x32 layout col=lane&31, row=(r&3)+8*(r>>2)+4*(lane>>5)
    float invsw = *invsw_p;
#pragma unroll
    for (int mt = 0; mt < 4; mt++) {
        int rowb = bm * 256 + wr * 128 + mt * 32 + (lh << 2);
        float sc[16];
#pragma unroll
        for (int r = 0; r < 16; r++)
            sc[r] = invsw / si[rowb + (r & 3) + ((r >> 2) << 3)];
#pragma unroll
        for (int nt = 0; nt < 2; nt++) {
            int col = bn * 128 + wc * 64 + nt * 32 + l31;
#pragma unroll
            for (int r = 0; r < 16; r++) {
                int row = rowb + (r & 3) + ((r >> 2) << 3);
                float vv = (float)acc[mt][nt][r] * sc[r];
                out[(size_t)row * N_DIM + col] = (float)(_Float16)vv;
            }
        }
    }
}

extern "C" void kernel_launch(void* const* d_in, const int* in_sizes, int n_in,
                              void* d_out, int out_size, void* d_ws, size_t ws_size,
                              hipStream_t stream) {
    const float* x = (const float*)d_in[0];
    const float* w = (const float*)d_in[1];
    float* out = (float*)d_out;
    char* ws = (char*)d_ws;

    double* part = (double*)ws;
    float* invsw = (float*)(ws + 2048);
    float* si = (float*)(ws + 4096);
    signed char* qw = (signed char*)(ws + 4096 + 65536);
    signed char* qx = qw + (size_t)N_DIM * K_DIM;

    k_wsum<<<256, 256, 0, stream>>>(w, part);
    k_wred<<<1, 256, 0, stream>>>(part, invsw);
    k_quant_x<<<4096, 256, 0, stream>>>(x, qx, si);
    k_quant_w<<<4096, 256, 0, stream>>>(w, qw, invsw);
    k_gemm<<<dim3(N_DIM / 128, M_DIM / 256), 256, 0, stream>>>(qx, qw, si, invsw, out);
}

// Round 3
// 330.404 us; speedup vs baseline: 1.1306x; 1.1306x over previous
//
#include <hip/hip_runtime.h>

#define K_DIM 2048
#define N_DIM 2048
#define M_DIM 16384

typedef int v4i __attribute__((ext_vector_type(4)));
typedef int v16i __attribute__((ext_vector_type(16)));

// ---------------- ws layout ----------------
// [0]       double part[256]      (2 KB)
// [2048]    float  invsw          (= clip(mean|W|,1e-5))
// [4096]    float  si[16384]      (64 KB)
// [69632]   int8   qw_t           (4 MiB)  tiled [bn(16)][ks(32)][k16(4)][row(128)][16B]
// [4263936] int8   qx_t           (32 MiB) tiled [bm(64)][ks(32)][k16(4)][row(256)][16B]

__device__ __forceinline__ void lds16(const void* g, void* l) {
    __builtin_amdgcn_global_load_lds(
        (const __attribute__((address_space(1))) unsigned int*)g,
        (__attribute__((address_space(3))) unsigned int*)l,
        16, 0, 0);
}

// ---------- kernel 1: per-block |W| partial sums ----------
__global__ __launch_bounds__(256) void k_wsum(const float* __restrict__ w,
                                              double* __restrict__ part) {
    int tid = blockIdx.x * 256 + threadIdx.x;
    const float4* w4 = (const float4*)w;
    double s = 0.0;
    for (int i = tid; i < (N_DIM * K_DIM / 4); i += 65536) {
        float4 v = w4[i];
        s += (double)fabsf(v.x);
        s += (double)fabsf(v.y);
        s += (double)fabsf(v.z);
        s += (double)fabsf(v.w);
    }
#pragma unroll
    for (int off = 32; off; off >>= 1) s += __shfl_xor(s, off, 64);
    __shared__ double sp[4];
    int lane = threadIdx.x & 63, wv = threadIdx.x >> 6;
    if (lane == 0) sp[wv] = s;
    __syncthreads();
    if (threadIdx.x == 0) part[blockIdx.x] = sp[0] + sp[1] + sp[2] + sp[3];
}

// ---------- kernel 2: reduce partials inline + ternary-quantize W (swizzled out) ----------
// 512 blocks x 256 threads; each wave quantizes one row of W into qw_t.
__global__ __launch_bounds__(256) void k_quant_w(const float* __restrict__ w,
                                                 signed char* __restrict__ qw_t,
                                                 const double* __restrict__ part,
                                                 float* __restrict__ invsw_out) {
    // deterministic re-reduction of the 256 partials (identical in every block)
    double s = part[threadIdx.x];
#pragma unroll
    for (int off = 32; off; off >>= 1) s += __shfl_xor(s, off, 64);
    __shared__ double sp[4];
    __shared__ float s_invsw;
    int lane = threadIdx.x & 63, wv = threadIdx.x >> 6;
    if (lane == 0) sp[wv] = s;
    __syncthreads();
    if (threadIdx.x == 0) {
        double total = sp[0] + sp[1] + sp[2] + sp[3];
        float mean = (float)(total * (1.0 / (double)(N_DIM * K_DIM)));
        s_invsw = fmaxf(mean, 1e-5f);
        if (blockIdx.x == 0) *invsw_out = s_invsw;
    }
    __syncthreads();
    float sw = 1.0f / s_invsw;  // reference's sw

    int row = blockIdx.x * 4 + wv;           // 0..2047
    const float4* wr_ = (const float4*)(w + (size_t)row * K_DIM);
    int bn = row >> 7, ri = row & 127;
    // dest: bn*262144 + ks*8192 + k16*2048 + ri*16 + 4*(lane&3); ks = 4c + (lane>>4)
    signed char* base = qw_t + (size_t)bn * 262144 + (((lane >> 2) & 3) << 11) + (ri << 4) + ((lane & 3) << 2);
    int ksBase = lane >> 4;
#pragma unroll
    for (int c = 0; c < 8; c++) {
        float4 v = wr_[c * 64 + lane];
        int q0 = (int)fminf(fmaxf(rintf(v.x * sw), -1.f), 1.f);
        int q1 = (int)fminf(fmaxf(rintf(v.y * sw), -1.f), 1.f);
        int q2 = (int)fminf(fmaxf(rintf(v.z * sw), -1.f), 1.f);
        int q3 = (int)fminf(fmaxf(rintf(v.w * sw), -1.f), 1.f);
        int q = (q0 & 255) | ((q1 & 255) << 8) | ((q2 & 255) << 16) | ((q3 & 255) << 24);
        *(int*)(base + (size_t)(4 * c + ksBase) * 8192) = q;
    }
}

// ---------- kernel 3: per-row int8-quantize X (swizzled out) ----------
__global__ __launch_bounds__(256) void k_quant_x(const float* __restrict__ x,
                                                 signed char* __restrict__ qx_t,
                                                 float* __restrict__ si_out) {
    int row = blockIdx.x * 4 + (threadIdx.x >> 6);
    int lane = threadIdx.x & 63;
    const float4* xr = (const float4*)(x + (size_t)row * K_DIM);
    float4 v[8];
    float mx = 0.f;
#pragma unroll
    for (int c = 0; c < 8; c++) {
        v[c] = xr[c * 64 + lane];
        mx = fmaxf(mx, fmaxf(fmaxf(fabsf(v[c].x), fabsf(v[c].y)),
                             fmaxf(fabsf(v[c].z), fabsf(v[c].w))));
    }
#pragma unroll
    for (int off = 32; off; off >>= 1) mx = fmaxf(mx, __shfl_xor(mx, off, 64));
    float si = 127.0f / fmaxf(mx, 1e-5f);  // bit-exact vs reference
    if (lane == 0) si_out[row] = si;

    int bm = row >> 8, ri = row & 255;
    // dest: bm*524288 + ks*16384 + k16*4096 + ri*16 + 4*(lane&3); ks = 4c + (lane>>4)
    signed char* base = qx_t + (size_t)bm * 524288 + (((lane >> 2) & 3) << 12) + (ri << 4) + ((lane & 3) << 2);
    int ksBase = lane >> 4;
#pragma unroll
    for (int c = 0; c < 8; c++) {
        int q0 = (int)fminf(fmaxf(rintf(v[c].x * si), -128.f), 127.f);
        int q1 = (int)fminf(fmaxf(rintf(v[c].y * si), -128.f), 127.f);
        int q2 = (int)fminf(fmaxf(rintf(v[c].z * si), -128.f), 127.f);
        int q3 = (int)fminf(fmaxf(rintf(v[c].w * si), -128.f), 127.f);
        int q = (q0 & 255) | ((q1 & 255) << 8) | ((q2 & 255) << 16) | ((q3 & 255) << 24);
        *(int*)(base + (size_t)(4 * c + ksBase) * 16384) = q;
    }
}

// ---------- kernel 4: int8 GEMM, 256x128 block, 32x32x32 MFMA ----------
// Staging is fully coalesced (tiles are stored in exact LDS-image order);
// LDS image identical to round 2 (verified correct, 0 bank conflicts).
__global__ __launch_bounds__(256, 2) void k_gemm(const signed char* __restrict__ qx_t,
                                                 const signed char* __restrict__ qw_t,
                                                 const float* __restrict__ si,
                                                 const float* __restrict__ invsw_p,
                                                 float* __restrict__ out) {
    __shared__ __align__(16) signed char As[16384];  // [k16(4)][row(256)][16B]
    __shared__ __align__(16) signed char Bs[8192];   // [k16(4)][row(128)][16B]
    const int t = threadIdx.x;
    const int lane = t & 63, wv = t >> 6;
    const int wr = wv >> 1, wc = wv & 1;   // 2x2 wave grid; wave tile 128x64
    const int l31 = lane & 31, lh = lane >> 5;
    const int bn = blockIdx.x, bm = blockIdx.y;

    const signed char* aT = qx_t + (size_t)bm * 524288;
    const signed char* bT = qw_t + (size_t)bn * 262144;
    const int t16 = t << 4;

    v16i acc[4][2] = {};

    for (int ks = 0; ks < 32; ks++) {
        const signed char* aS = aT + (ks << 14);
        const signed char* bS = bT + (ks << 13);
        lds16(aS + t16,          As + t16);
        lds16(aS + 4096 + t16,   As + 4096 + t16);
        lds16(aS + 8192 + t16,   As + 8192 + t16);
        lds16(aS + 12288 + t16,  As + 12288 + t16);
        lds16(bS + t16,          Bs + t16);
        lds16(bS + 4096 + t16,   Bs + 4096 + t16);
        __syncthreads();

#pragma unroll
        for (int ks2 = 0; ks2 < 2; ks2++) {
            v4i af[4], bf[2];
#pragma unroll
            for (int mt = 0; mt < 4; mt++)
                af[mt] = *(const v4i*)(As + (((ks2 * 2 + lh) * 256 + wr * 128 + mt * 32 + l31) << 4));
#pragma unroll
            for (int nt = 0; nt < 2; nt++)
                bf[nt] = *(const v4i*)(Bs + (((ks2 * 2 + lh) * 128 + wc * 64 + nt * 32 + l31) << 4));
#pragma unroll
            for (int mt = 0; mt < 4; mt++)
#pragma unroll
                for (int nt = 0; nt < 2; nt++)
                    acc[mt][nt] = __builtin_amdgcn_mfma_i32_32x32x32_i8(af[mt], bf[nt], acc[mt][nt], 0, 0, 0);
        }
        __syncthreads();
    }

    // epilogue: C/D 32x32 layout col=lane&31, row=(r&3)+8*(r>>2)+4*(lane>>5)
    float invsw = *invsw_p;
#pragma unroll
    for (int mt = 0; mt < 4; mt++) {
        int rowb = bm * 256 + wr * 128 + mt * 32 + (lh << 2);
        float sc[16];
#pragma unroll
        for (int r = 0; r < 16; r++)
            sc[r] = invsw / si[rowb + (r & 3) + ((r >> 2) << 3)];
#pragma unroll
        for (int nt = 0; nt < 2; nt++) {
            int col = bn * 128 + wc * 64 + nt * 32 + l31;
#pragma unroll
            for (int r = 0; r < 16; r++) {
                int row = rowb + (r & 3) + ((r >> 2) << 3);
                float vv = (float)acc[mt][nt][r] * sc[r];
                out[(size_t)row * N_DIM + col] = (float)(_Float16)vv;
            }
        }
    }
}

extern "C" void kernel_launch(void* const* d_in, const int* in_sizes, int n_in,
                              void* d_out, int out_size, void* d_ws, size_t ws_size,
                              hipStream_t stream) {
    const float* x = (const float*)d_in[0];
    const float* w = (const float*)d_in[1];
    float* out = (float*)d_out;
    char* ws = (char*)d_ws;

    double* part = (double*)ws;
    float* invsw = (float*)(ws + 2048);
    float* si = (float*)(ws + 4096);
    signed char* qw_t = (signed char*)(ws + 4096 + 65536);
    signed char* qx_t = qw_t + (size_t)N_DIM * K_DIM;

    k_wsum<<<256, 256, 0, stream>>>(w, part);
    k_quant_x<<<4096, 256, 0, stream>>>(x, qx_t, si);
    k_quant_w<<<512, 256, 0, stream>>>(w, qw_t, part, invsw);
    k_gemm<<<dim3(N_DIM / 128, M_DIM / 256), 256, 0, stream>>>(qx_t, qw_t, si, invsw, out);
}